// Round 3
// baseline (163.459 us; speedup 1.0000x reference)
//
#include <hip/hip_runtime.h>
#include <hip/hip_cooperative_groups.h>
#include <math.h>

namespace cg = cooperative_groups;

// SurvLoss: Cox partial-likelihood loss with tie grouping.
// |Y| is an integer in [1,2000]; sorted order is -2000..-1,1..2000, so
//   loss2 = sum_t n_events(t) * log(negExpTotal + prefix_{u<=t} posExp(u))
//   loss1 = sum(Yhat * [Y>0]);  obs = count(Y>0)
// => 2000-bucket histogram + tiny double-precision scan. No sort.
//
// R2: non-atomic per-block histogram dumps + tiled tree-reduce kernels.
// R4: occupancy fix (1024-thr blocks, pipelined loads), u16 dump, shfl final.
// R5 (this round): counters showed the timed window is ~85us of harness
// workspace-poison fills (2x 268MB @ 6.3TB/s) + ~10us of our 3 kernels.
// So attack FIXED costs: fuse all 3 kernels into ONE cooperative launch
// (256 blocks = 1/CU) with grid.sync() between phases. Phase 2 gives each
// block exclusive ownership of 8 histogram columns -> zero atomics, no
// pre-zeroing, dump shrinks to 3MB. Saves 2 launch gaps + merge atomics.

#define NBLK 256
#define NT 1024
#define NH 2048
#define RSTR 129  // padded reduce stride (129%32==1 -> conflict-free banks)

__global__ __launch_bounds__(NT) void surv_all(
    const float* __restrict__ Yhat, const float* __restrict__ Y, int n4,
    float* __restrict__ Exp, unsigned short* __restrict__ Evt,
    float* __restrict__ gExp, unsigned int* __restrict__ gEvt,
    double* __restrict__ negPart, double* __restrict__ loss1Part,
    unsigned long long* __restrict__ obsPart, float* __restrict__ out)
{
    cg::grid_group grid = cg::this_grid();
    const int tid = threadIdx.x;
    const int lane = tid & 63, wid = tid >> 6;

    __shared__ float sExp[NH];
    __shared__ unsigned int sEvt[NH];
    __shared__ float sRedF[8 * RSTR];
    __shared__ unsigned int sRedU[8 * RSTR];
    __shared__ float wNeg[NT / 64], wL1[NT / 64];
    __shared__ unsigned int wObs[NT / 64];
    __shared__ double sN[NT / 64], sL[NT / 64], sO[NT / 64], sWv[NT / 64], sZ[NT / 64];

    // ---------------- phase 1: per-block LDS histogram ----------------
    for (int i = tid; i < NH; i += NT) { sExp[i] = 0.f; sEvt[i] = 0u; }
    __syncthreads();

    float negSum = 0.f, loss1 = 0.f;
    unsigned int obs = 0;

    const float4* __restrict__ Y4 = (const float4*)Y;
    const float4* __restrict__ H4 = (const float4*)Yhat;
    const int stride = NBLK * NT;

#define PROC(yv, hv)                                     \
    {                                                    \
        float ys[4] = {yv.x, yv.y, yv.z, yv.w};          \
        float hs[4] = {hv.x, hv.y, hv.z, hv.w};          \
        _Pragma("unroll")                                \
        for (int c = 0; c < 4; ++c) {                    \
            float e = __expf(hs[c]);                     \
            if (ys[c] > 0.f) {                           \
                int t = (int)ys[c];                      \
                atomicAdd(&sExp[t], e);                  \
                atomicAdd(&sEvt[t], 1u);                 \
                loss1 += hs[c];                          \
                obs += 1u;                               \
            } else {                                     \
                negSum += e;                             \
            }                                            \
        }                                                \
    }

    int i = blockIdx.x * NT + tid;
    // 4-deep pipelined main loop: 8 outstanding 16B loads per thread
    for (; i + 3 * stride < n4; i += 4 * stride) {
        float4 y0 = Y4[i];                float4 h0 = H4[i];
        float4 y1 = Y4[i + stride];       float4 h1 = H4[i + stride];
        float4 y2 = Y4[i + 2 * stride];   float4 h2 = H4[i + 2 * stride];
        float4 y3 = Y4[i + 3 * stride];   float4 h3 = H4[i + 3 * stride];
        PROC(y0, h0); PROC(y1, h1); PROC(y2, h2); PROC(y3, h3);
    }
    for (; i < n4; i += stride) {
        float4 y = Y4[i];
        float4 h = H4[i];
        PROC(y, h);
    }
#undef PROC

    // wave (64-lane) reduce of scalars, then block partial -> global
    #pragma unroll
    for (int off = 32; off > 0; off >>= 1) {
        negSum += __shfl_down(negSum, off);
        loss1  += __shfl_down(loss1, off);
        obs    += __shfl_down(obs, off);
    }
    if (lane == 0) { wNeg[wid] = negSum; wL1[wid] = loss1; wObs[wid] = obs; }
    __syncthreads();  // also guarantees all LDS hist atomics are complete
    if (tid == 0) {
        double nn = 0.0, ll = 0.0; unsigned long long oo = 0ull;
        #pragma unroll
        for (int w = 0; w < NT / 64; ++w) {
            nn += (double)wNeg[w]; ll += (double)wL1[w]; oo += wObs[w];
        }
        negPart[blockIdx.x] = nn;
        loss1Part[blockIdx.x] = ll;
        obsPart[blockIdx.x] = oo;
    }

    // non-atomic coalesced dump of this block's histogram row
    float* __restrict__ myExp = Exp + (size_t)blockIdx.x * NH;
    unsigned short* __restrict__ myEvt = Evt + (size_t)blockIdx.x * NH;
    for (int i2 = tid; i2 < NH; i2 += NT) {
        myExp[i2] = sExp[i2];
        myEvt[i2] = (unsigned short)sEvt[i2];  // <=16384 events/block, fits u16
    }

    grid.sync();

    // ---- phase 2: block b exclusively owns cols [8b, 8b+8) -> no atomics ----
    {
        const int c = tid & 7;          // col within this block's 8
        const int r = tid >> 3;         // 0..127 (row-pair index)
        const int col = blockIdx.x * 8 + c;
        float fa = Exp[(size_t)r * NH + col] + Exp[(size_t)(r + 128) * NH + col];
        unsigned int ua = (unsigned int)Evt[(size_t)r * NH + col]
                        + (unsigned int)Evt[(size_t)(r + 128) * NH + col];
        sRedF[c * RSTR + r] = fa;
        sRedU[c * RSTR + r] = ua;
        __syncthreads();
        #pragma unroll
        for (int off = 64; off > 0; off >>= 1) {
            if (r < off) {
                sRedF[c * RSTR + r] += sRedF[c * RSTR + r + off];
                sRedU[c * RSTR + r] += sRedU[c * RSTR + r + off];
            }
            __syncthreads();
        }
        if (r == 0) { gExp[col] = sRedF[c * RSTR]; gEvt[col] = sRedU[c * RSTR]; }
    }

    grid.sync();

    // ---------------- phase 3: block 0 does the tiny scan ----------------
    if (blockIdx.x != 0) return;

    // reduce per-block scalar partials (NBLK == 256 <= NT)
    double nP = (tid < NBLK) ? negPart[tid] : 0.0;
    double lP = (tid < NBLK) ? loss1Part[tid] : 0.0;
    double oP = (tid < NBLK) ? (double)obsPart[tid] : 0.0;
    #pragma unroll
    for (int off = 32; off > 0; off >>= 1) {
        nP += __shfl_down(nP, off);
        lP += __shfl_down(lP, off);
        oP += __shfl_down(oP, off);
    }
    if (lane == 0) { sN[wid] = nP; sL[wid] = lP; sO[wid] = oP; }

    // each thread owns 2 consecutive buckets (ascending t across threads)
    const double pe0 = (double)gExp[2 * tid];
    const double pe1 = (double)gExp[2 * tid + 1];
    const unsigned int e0 = gEvt[2 * tid];
    const unsigned int e1 = gEvt[2 * tid + 1];
    const double csum = pe0 + pe1;

    // wave-inclusive shfl scan of per-thread chunk sums
    double x = csum;
    #pragma unroll
    for (int off = 1; off < 64; off <<= 1) {
        double t = __shfl_up(x, off);
        if (lane >= off) x += t;
    }
    if (lane == 63) sWv[wid] = x;
    __syncthreads();

    double negTotal = 0.0;
    #pragma unroll
    for (int w = 0; w < NT / 64; ++w) negTotal += sN[w];
    double waveOff = 0.0;
    for (int w = 0; w < wid; ++w) waveOff += sWv[w];

    double prefix = negTotal + waveOff + (x - csum);  // exclusive prefix
    double loss2 = 0.0;
    prefix += pe0; if (e0) loss2 += (double)e0 * log(prefix);
    prefix += pe1; if (e1) loss2 += (double)e1 * log(prefix);

    #pragma unroll
    for (int off = 32; off > 0; off >>= 1) loss2 += __shfl_down(loss2, off);
    if (lane == 0) sZ[wid] = loss2;
    __syncthreads();

    if (tid == 0) {
        double l2 = 0.0, l1 = 0.0, ob = 0.0;
        #pragma unroll
        for (int w = 0; w < NT / 64; ++w) { l2 += sZ[w]; l1 += sL[w]; ob += sO[w]; }
        out[0] = (float)((l2 - l1) / ob);
    }
}

extern "C" void kernel_launch(void* const* d_in, const int* in_sizes, int n_in,
                              void* d_out, int out_size, void* d_ws, size_t ws_size,
                              hipStream_t stream)
{
    const float* Yhat = (const float*)d_in[0];
    const float* Y    = (const float*)d_in[1];
    int n4 = in_sizes[0] / 4;

    char* ws = (char*)d_ws;
    float* Exp            = (float*)(ws);                                   // 2 MB
    unsigned short* Evt   = (unsigned short*)(ws + (size_t)NBLK * NH * 4);  // 1 MB
    char* tail            = ws + (size_t)NBLK * NH * 6;
    float* gExp           = (float*)(tail);                                 // 8 KB
    unsigned int* gEvt    = (unsigned int*)(tail + NH * 4);                 // 8 KB
    double* negPart       = (double*)(tail + NH * 8);                       // 2 KB
    double* loss1Part     = (double*)(tail + NH * 8 + NBLK * 8);            // 2 KB
    unsigned long long* obsPart =
        (unsigned long long*)(tail + NH * 8 + 2 * NBLK * 8);                // 2 KB
    float* out = (float*)d_out;

    void* args[] = {(void*)&Yhat, (void*)&Y, (void*)&n4, (void*)&Exp, (void*)&Evt,
                    (void*)&gExp, (void*)&gEvt, (void*)&negPart, (void*)&loss1Part,
                    (void*)&obsPart, (void*)&out};
    hipLaunchCooperativeKernel((void*)surv_all, dim3(NBLK), dim3(NT), args, 0, stream);
}

// Round 4
// 128.586 us; speedup vs baseline: 1.2712x; 1.2712x over previous
//
#include <hip/hip_runtime.h>
#include <math.h>

// SurvLoss: Cox partial-likelihood loss with tie grouping.
// |Y| is an integer in [1,2000]; sorted order is -2000..-1,1..2000, so
//   loss2 = sum_t n_events(t) * log(negExpTotal + prefix_{u<=t} posExp(u))
//   loss1 = sum(Yhat * [Y>0]);  obs = count(Y>0)
// => 2000-bucket histogram + tiny double-precision scan. No sort.
//
// R2: non-atomic per-block histogram dumps + tiled tree-reduce kernels (95.2us).
// R4: occupancy fix (1024-thr blocks, pipelined loads), u16 dump, shfl final.
// R5: FAILED (163us): cooperative fusion. grid.sync() across 8 non-coherent
//     XCD L2s costs ~35us each (kernel ran 79.6us even with inputs fully
//     LLC-cached, VALUBusy 2.2%) -> never use coop launch to save ~2us gaps.
// R6 (this round): revert to proven R4 3-kernel structure; fuse ONLY
//     reduce+final via last-block-done pattern (agent-scope acq_rel atomic
//     counter; no spin, no grid.sync). Saves one launch + gap; final reads
//     gExp L2-warm. Counter + gExp/gEvt zeroed by hist block 0 (stream-
//     ordered before reduce -> re-poison-safe).

#define NBLK 512     // hist blocks
#define NT 1024      // hist block size
#define NRB 512      // reduce blocks
#define NTF 256      // reduce/final block size
#define NH 2048

__global__ __launch_bounds__(NT) void surv_hist(
    const float* __restrict__ Yhat, const float* __restrict__ Y, int n4,
    float* __restrict__ Exp, unsigned short* __restrict__ Evt,
    float* __restrict__ gExp, unsigned int* __restrict__ gEvt,
    unsigned int* __restrict__ doneCtr,
    double* __restrict__ negPart, double* __restrict__ loss1Part,
    unsigned long long* __restrict__ obsPart)
{
    __shared__ float sExp[NH];
    __shared__ unsigned int sEvt[NH];
    for (int i = threadIdx.x; i < NH; i += NT) { sExp[i] = 0.f; sEvt[i] = 0u; }
    // block 0 zeroes the merged histogram + done counter (read only by the
    // reduce kernel, which is stream-ordered after this one -> no race)
    if (blockIdx.x == 0) {
        for (int i = threadIdx.x; i < NH; i += NT) { gExp[i] = 0.f; gEvt[i] = 0u; }
        if (threadIdx.x == 0) *doneCtr = 0u;
    }
    __syncthreads();

    float negSum = 0.f, loss1 = 0.f;
    unsigned int obs = 0;

    const float4* __restrict__ Y4 = (const float4*)Y;
    const float4* __restrict__ H4 = (const float4*)Yhat;
    const int stride = NBLK * NT;

#define PROC(yv, hv)                                     \
    {                                                    \
        float ys[4] = {yv.x, yv.y, yv.z, yv.w};          \
        float hs[4] = {hv.x, hv.y, hv.z, hv.w};          \
        _Pragma("unroll")                                \
        for (int c = 0; c < 4; ++c) {                    \
            float e = __expf(hs[c]);                     \
            if (ys[c] > 0.f) {                           \
                int t = (int)ys[c];                      \
                atomicAdd(&sExp[t], e);                  \
                atomicAdd(&sEvt[t], 1u);                 \
                loss1 += hs[c];                          \
                obs += 1u;                               \
            } else {                                     \
                negSum += e;                             \
            }                                            \
        }                                                \
    }

    int i = blockIdx.x * NT + threadIdx.x;
    // 2-deep pipelined main loop: 4 outstanding 16B loads per thread
    for (; i + stride < n4; i += 2 * stride) {
        float4 y0 = Y4[i];
        float4 h0 = H4[i];
        float4 y1 = Y4[i + stride];
        float4 h1 = H4[i + stride];
        PROC(y0, h0);
        PROC(y1, h1);
    }
    for (; i < n4; i += stride) {
        float4 y = Y4[i];
        float4 h = H4[i];
        PROC(y, h);
    }
#undef PROC

    // wave (64-lane) reduce of scalars
    #pragma unroll
    for (int off = 32; off > 0; off >>= 1) {
        negSum += __shfl_down(negSum, off);
        loss1  += __shfl_down(loss1, off);
        obs    += __shfl_down(obs, off);
    }
    __shared__ float wNeg[NT / 64], wL1[NT / 64];
    __shared__ unsigned int wObs[NT / 64];
    const int lane = threadIdx.x & 63, wid = threadIdx.x >> 6;
    if (lane == 0) { wNeg[wid] = negSum; wL1[wid] = loss1; wObs[wid] = obs; }
    __syncthreads();  // also guarantees all LDS hist atomics are complete
    if (threadIdx.x == 0) {
        double nn = 0.0, ll = 0.0; unsigned long long oo = 0ull;
        #pragma unroll
        for (int w = 0; w < NT / 64; ++w) {
            nn += (double)wNeg[w]; ll += (double)wL1[w]; oo += wObs[w];
        }
        negPart[blockIdx.x] = nn;
        loss1Part[blockIdx.x] = ll;
        obsPart[blockIdx.x] = oo;
    }

    // non-atomic coalesced dump of this block's histogram row
    float* __restrict__ myExp = Exp + (size_t)blockIdx.x * NH;
    unsigned short* __restrict__ myEvt = Evt + (size_t)blockIdx.x * NH;
    for (int i2 = threadIdx.x; i2 < NH; i2 += NT) {
        myExp[i2] = sExp[i2];
        myEvt[i2] = (unsigned short)sEvt[i2];  // <=8192 events/block, fits u16
    }
}

// Sum the 512 x 2048 per-block histograms down to one 2048-bucket histogram,
// then the LAST block to finish computes the final scalar loss inline.
// Grid = 512 blocks: 8 column-chunks (256 cols each) x 64 row-chunks (8 rows).
__global__ __launch_bounds__(NTF) void surv_reduce_final(
    const float* __restrict__ Exp, const unsigned short* __restrict__ Evt,
    float* __restrict__ gExp, unsigned int* __restrict__ gEvt,
    unsigned int* __restrict__ doneCtr,
    const double* __restrict__ negPart, const double* __restrict__ loss1Part,
    const unsigned long long* __restrict__ obsPart, float* __restrict__ out)
{
    const int tid = threadIdx.x;
    {
        const int col = (blockIdx.x & 7) * NTF + tid;
        const int r0 = (blockIdx.x >> 3) * 8;
        float a = 0.f;
        unsigned int c = 0u;
        #pragma unroll
        for (int r = 0; r < 8; ++r) {
            a += Exp[(size_t)(r0 + r) * NH + col];
            c += (unsigned int)Evt[(size_t)(r0 + r) * NH + col];
        }
        atomicAdd(&gExp[col], a);   // device-scope, performed at LLC
        atomicAdd(&gEvt[col], c);
    }

    // last-block-done: acq_rel agent-scope counter. The acquire on the last
    // block invalidates its caches, so its plain reads below see all blocks'
    // LLC-resident atomic results. No spin -> no deadlock risk.
    __shared__ unsigned int isLast;
    __threadfence();                 // release this block's atomics
    __syncthreads();
    if (tid == 0) {
        unsigned int prev = __hip_atomic_fetch_add(
            doneCtr, 1u, __ATOMIC_ACQ_REL, __HIP_MEMORY_SCOPE_AGENT);
        isLast = (prev == (unsigned int)(NRB - 1)) ? 1u : 0u;
    }
    __syncthreads();
    if (!isLast) return;

    // ---------------- final scalar loss (one block, NTF=256) ----------------
    const int lane = tid & 63, wid = tid >> 6;

    // reduce per-block scalar partials (NBLK == 2*NTF), shfl within wave
    double nP = negPart[tid] + negPart[tid + NTF];
    double lP = loss1Part[tid] + loss1Part[tid + NTF];
    double oP = (double)(obsPart[tid] + obsPart[tid + NTF]);
    #pragma unroll
    for (int off = 32; off > 0; off >>= 1) {
        nP += __shfl_down(nP, off);
        lP += __shfl_down(lP, off);
        oP += __shfl_down(oP, off);
    }
    __shared__ double sN[4], sL[4], sO[4], sW[4], sZ[4];
    if (lane == 0) { sN[wid] = nP; sL[wid] = lP; sO[wid] = oP; }

    // each thread owns 8 consecutive buckets (ascending t across threads)
    const int C = NH / NTF;  // 8
    double pe[C]; unsigned int ev[C];
    double csum = 0.0;
    const int base = tid * C;
    #pragma unroll
    for (int j = 0; j < C; ++j) {
        pe[j] = (double)gExp[base + j];
        ev[j] = gEvt[base + j];
        csum += pe[j];
    }

    // wave-inclusive shfl scan of per-thread chunk sums
    double x = csum;
    #pragma unroll
    for (int off = 1; off < 64; off <<= 1) {
        double t = __shfl_up(x, off);
        if (lane >= off) x += t;
    }
    if (lane == 63) sW[wid] = x;
    __syncthreads();

    const double negTotal = sN[0] + sN[1] + sN[2] + sN[3];
    const double loss1    = sL[0] + sL[1] + sL[2] + sL[3];
    const double obs      = sO[0] + sO[1] + sO[2] + sO[3];
    double waveOff = 0.0;
    for (int w = 0; w < wid; ++w) waveOff += sW[w];

    double prefix = negTotal + waveOff + (x - csum);  // exclusive prefix
    double loss2 = 0.0;
    #pragma unroll
    for (int j = 0; j < C; ++j) {
        prefix += pe[j];
        if (ev[j]) loss2 += (double)ev[j] * log(prefix);
    }

    #pragma unroll
    for (int off = 32; off > 0; off >>= 1) loss2 += __shfl_down(loss2, off);
    if (lane == 0) sZ[wid] = loss2;
    __syncthreads();
    if (tid == 0)
        out[0] = (float)((sZ[0] + sZ[1] + sZ[2] + sZ[3] - loss1) / obs);
}

extern "C" void kernel_launch(void* const* d_in, const int* in_sizes, int n_in,
                              void* d_out, int out_size, void* d_ws, size_t ws_size,
                              hipStream_t stream)
{
    const float* Yhat = (const float*)d_in[0];
    const float* Y    = (const float*)d_in[1];
    const int n = in_sizes[0];

    char* ws = (char*)d_ws;
    // layout: per-block hist dumps, then final histogram, then scalar partials
    float* Exp            = (float*)(ws);                                   // 4 MB
    unsigned short* Evt   = (unsigned short*)(ws + (size_t)NBLK * NH * 4);  // 2 MB
    char* tail            = ws + (size_t)NBLK * NH * 6;
    float* gExp           = (float*)(tail);                                 // 8 KB
    unsigned int* gEvt    = (unsigned int*)(tail + NH * 4);                 // 8 KB
    double* negPart       = (double*)(tail + NH * 8);                       // 4 KB
    double* loss1Part     = (double*)(tail + NH * 8 + NBLK * 8);            // 4 KB
    unsigned long long* obsPart =
        (unsigned long long*)(tail + NH * 8 + 2 * NBLK * 8);                // 4 KB
    unsigned int* doneCtr =
        (unsigned int*)(tail + NH * 8 + 3 * NBLK * 8);                      // 4 B

    surv_hist<<<NBLK, NT, 0, stream>>>(Yhat, Y, n / 4, Exp, Evt,
                                       gExp, gEvt, doneCtr,
                                       negPart, loss1Part, obsPart);
    surv_reduce_final<<<NRB, NTF, 0, stream>>>(Exp, Evt, gExp, gEvt, doneCtr,
                                               negPart, loss1Part, obsPart,
                                               (float*)d_out);
}

// Round 5
// 94.635 us; speedup vs baseline: 1.7272x; 1.3587x over previous
//
#include <hip/hip_runtime.h>
#include <math.h>

// SurvLoss: Cox partial-likelihood loss with tie grouping.
// |Y| is an integer in [1,2000]; sorted order is -2000..-1,1..2000, so
//   loss2 = sum_t n_events(t) * log(negExpTotal + prefix_{u<=t} posExp(u))
//   loss1 = sum(Yhat * [Y>0]);  obs = count(Y>0)
// => 2000-bucket histogram + tiny double-precision scan. No sort.
//
// Session ledger:
// R2: non-atomic per-block hist dumps + tiled reduce + tiny final = 95.18us.
//     Timed window = ~85.5us harness workspace re-poison (2x 268MB fills at
//     HBM roofline, outside our control) + ~9.7us our kernels.
// R5: FAILED (163us): cooperative fusion; grid.sync() across 8 non-coherent
//     XCD L2s costs ~35us each (coop kernel 79.6us even fully LLC-cached).
// R6: FAILED (128.6us): last-block-done fusion; per-block __threadfence +
//     agent-scope acq_rel RMW = device-scope cache maintenance x512 blocks
//     = 46us kernel doing 3MB of work (VALUBusy 0.3%).
// R7 (this round): clean revert to the proven R2 structure. Controllable
//     floor is ~93.5us (5.1us input read + ~3us reduce/final/gaps + fills);
//     R2's 95.18 is within ~2% -> structural roofline once reconfirmed.

#define NBLK 512     // hist blocks
#define NT 1024      // hist block size
#define NTF 256      // final/reduce block size
#define NH 2048

__global__ __launch_bounds__(NT) void surv_hist(
    const float* __restrict__ Yhat, const float* __restrict__ Y, int n4,
    float* __restrict__ Exp, unsigned short* __restrict__ Evt,
    float* __restrict__ gExp, unsigned int* __restrict__ gEvt,
    double* __restrict__ negPart, double* __restrict__ loss1Part,
    unsigned long long* __restrict__ obsPart)
{
    __shared__ float sExp[NH];
    __shared__ unsigned int sEvt[NH];
    for (int i = threadIdx.x; i < NH; i += NT) { sExp[i] = 0.f; sEvt[i] = 0u; }
    // block 0 also zeroes the final merged histogram (read only by
    // surv_reduce, which is stream-ordered after this kernel -> no race)
    if (blockIdx.x == 0) {
        for (int i = threadIdx.x; i < NH; i += NT) { gExp[i] = 0.f; gEvt[i] = 0u; }
    }
    __syncthreads();

    float negSum = 0.f, loss1 = 0.f;
    unsigned int obs = 0;

    const float4* __restrict__ Y4 = (const float4*)Y;
    const float4* __restrict__ H4 = (const float4*)Yhat;
    const int stride = NBLK * NT;

#define PROC(yv, hv)                                     \
    {                                                    \
        float ys[4] = {yv.x, yv.y, yv.z, yv.w};          \
        float hs[4] = {hv.x, hv.y, hv.z, hv.w};          \
        _Pragma("unroll")                                \
        for (int c = 0; c < 4; ++c) {                    \
            float e = __expf(hs[c]);                     \
            if (ys[c] > 0.f) {                           \
                int t = (int)ys[c];                      \
                atomicAdd(&sExp[t], e);                  \
                atomicAdd(&sEvt[t], 1u);                 \
                loss1 += hs[c];                          \
                obs += 1u;                               \
            } else {                                     \
                negSum += e;                             \
            }                                            \
        }                                                \
    }

    int i = blockIdx.x * NT + threadIdx.x;
    // 2-deep pipelined main loop: 4 outstanding 16B loads per thread
    for (; i + stride < n4; i += 2 * stride) {
        float4 y0 = Y4[i];
        float4 h0 = H4[i];
        float4 y1 = Y4[i + stride];
        float4 h1 = H4[i + stride];
        PROC(y0, h0);
        PROC(y1, h1);
    }
    for (; i < n4; i += stride) {
        float4 y = Y4[i];
        float4 h = H4[i];
        PROC(y, h);
    }
#undef PROC

    // wave (64-lane) reduce of scalars
    #pragma unroll
    for (int off = 32; off > 0; off >>= 1) {
        negSum += __shfl_down(negSum, off);
        loss1  += __shfl_down(loss1, off);
        obs    += __shfl_down(obs, off);
    }
    __shared__ float wNeg[NT / 64], wL1[NT / 64];
    __shared__ unsigned int wObs[NT / 64];
    const int lane = threadIdx.x & 63, wid = threadIdx.x >> 6;
    if (lane == 0) { wNeg[wid] = negSum; wL1[wid] = loss1; wObs[wid] = obs; }
    __syncthreads();  // also guarantees all LDS hist atomics are complete
    if (threadIdx.x == 0) {
        double nn = 0.0, ll = 0.0; unsigned long long oo = 0ull;
        #pragma unroll
        for (int w = 0; w < NT / 64; ++w) {
            nn += (double)wNeg[w]; ll += (double)wL1[w]; oo += wObs[w];
        }
        negPart[blockIdx.x] = nn;
        loss1Part[blockIdx.x] = ll;
        obsPart[blockIdx.x] = oo;
    }

    // non-atomic coalesced dump of this block's histogram row
    float* __restrict__ myExp = Exp + (size_t)blockIdx.x * NH;
    unsigned short* __restrict__ myEvt = Evt + (size_t)blockIdx.x * NH;
    for (int i2 = threadIdx.x; i2 < NH; i2 += NT) {
        myExp[i2] = sExp[i2];
        myEvt[i2] = (unsigned short)sEvt[i2];  // <=8192 events/block, fits u16
    }
}

// Sum the 512 x 2048 per-block histograms down to one 2048-bucket histogram.
// Grid = 512 blocks: 8 column-chunks (256 cols each) x 64 row-chunks (8 rows).
// One atomicAdd per thread per array -> 64 contenders per address.
__global__ __launch_bounds__(NTF) void surv_reduce(
    const float* __restrict__ Exp, const unsigned short* __restrict__ Evt,
    float* __restrict__ gExp, unsigned int* __restrict__ gEvt)
{
    const int col = (blockIdx.x & 7) * NTF + threadIdx.x;
    const int r0 = (blockIdx.x >> 3) * 8;
    float a = 0.f;
    unsigned int c = 0u;
    #pragma unroll
    for (int r = 0; r < 8; ++r) {
        a += Exp[(size_t)(r0 + r) * NH + col];
        c += (unsigned int)Evt[(size_t)(r0 + r) * NH + col];
    }
    atomicAdd(&gExp[col], a);
    atomicAdd(&gEvt[col], c);
}

__global__ __launch_bounds__(NTF) void surv_final(
    const float* __restrict__ gExp, const unsigned int* __restrict__ gEvt,
    const double* __restrict__ negPart, const double* __restrict__ loss1Part,
    const unsigned long long* __restrict__ obsPart, float* __restrict__ out)
{
    const int tid = threadIdx.x;            // NTF = 256
    const int lane = tid & 63, wid = tid >> 6;

    // reduce per-block scalar partials (NBLK == 2*NTF), shfl within wave
    double nP = negPart[tid] + negPart[tid + NTF];
    double lP = loss1Part[tid] + loss1Part[tid + NTF];
    double oP = (double)(obsPart[tid] + obsPart[tid + NTF]);
    #pragma unroll
    for (int off = 32; off > 0; off >>= 1) {
        nP += __shfl_down(nP, off);
        lP += __shfl_down(lP, off);
        oP += __shfl_down(oP, off);
    }
    __shared__ double sN[4], sL[4], sO[4], sW[4], sZ[4];
    if (lane == 0) { sN[wid] = nP; sL[wid] = lP; sO[wid] = oP; }

    // each thread owns 8 consecutive buckets (ascending t across threads)
    const int C = NH / NTF;  // 8
    double pe[C]; unsigned int ev[C];
    double csum = 0.0;
    const int base = tid * C;
    #pragma unroll
    for (int j = 0; j < C; ++j) {
        pe[j] = (double)gExp[base + j];
        ev[j] = gEvt[base + j];
        csum += pe[j];
    }

    // wave-inclusive shfl scan of per-thread chunk sums
    double x = csum;
    #pragma unroll
    for (int off = 1; off < 64; off <<= 1) {
        double t = __shfl_up(x, off);
        if (lane >= off) x += t;
    }
    if (lane == 63) sW[wid] = x;
    __syncthreads();

    const double negTotal = sN[0] + sN[1] + sN[2] + sN[3];
    const double loss1    = sL[0] + sL[1] + sL[2] + sL[3];
    const double obs      = sO[0] + sO[1] + sO[2] + sO[3];
    double waveOff = 0.0;
    for (int w = 0; w < wid; ++w) waveOff += sW[w];

    double prefix = negTotal + waveOff + (x - csum);  // exclusive prefix
    double loss2 = 0.0;
    #pragma unroll
    for (int j = 0; j < C; ++j) {
        prefix += pe[j];
        if (ev[j]) loss2 += (double)ev[j] * log(prefix);
    }

    #pragma unroll
    for (int off = 32; off > 0; off >>= 1) loss2 += __shfl_down(loss2, off);
    if (lane == 0) sZ[wid] = loss2;
    __syncthreads();
    if (tid == 0)
        out[0] = (float)((sZ[0] + sZ[1] + sZ[2] + sZ[3] - loss1) / obs);
}

extern "C" void kernel_launch(void* const* d_in, const int* in_sizes, int n_in,
                              void* d_out, int out_size, void* d_ws, size_t ws_size,
                              hipStream_t stream)
{
    const float* Yhat = (const float*)d_in[0];
    const float* Y    = (const float*)d_in[1];
    const int n = in_sizes[0];

    char* ws = (char*)d_ws;
    // layout: per-block hist dumps, then final histogram, then scalar partials
    float* Exp            = (float*)(ws);                                   // 4 MB
    unsigned short* Evt   = (unsigned short*)(ws + (size_t)NBLK * NH * 4);  // 2 MB
    char* tail            = ws + (size_t)NBLK * NH * 6;
    float* gExp           = (float*)(tail);                                 // 8 KB
    unsigned int* gEvt    = (unsigned int*)(tail + NH * 4);                 // 8 KB
    double* negPart       = (double*)(tail + NH * 8);                       // 4 KB
    double* loss1Part     = (double*)(tail + NH * 8 + NBLK * 8);            // 4 KB
    unsigned long long* obsPart =
        (unsigned long long*)(tail + NH * 8 + 2 * NBLK * 8);                // 4 KB

    surv_hist<<<NBLK, NT, 0, stream>>>(Yhat, Y, n / 4, Exp, Evt,
                                       gExp, gEvt, negPart, loss1Part, obsPart);
    surv_reduce<<<512, NTF, 0, stream>>>(Exp, Evt, gExp, gEvt);
    surv_final<<<1, NTF, 0, stream>>>(gExp, gEvt, negPart, loss1Part, obsPart,
                                      (float*)d_out);
}